// Round 6
// baseline (777.687 us; speedup 1.0000x reference)
//
#include <hip/hip_runtime.h>
#include <cstdint>
#include <cstddef>

// Problem constants (reference: N=16384, DX1=DX2=1024, DH=2048)
#define NR 16384
#define DX 1024
#define DH 2048

typedef unsigned short u16;
typedef _Float16 half8 __attribute__((ext_vector_type(8)));
typedef _Float16 half4v __attribute__((ext_vector_type(4)));
typedef float f32x16 __attribute__((ext_vector_type(16)));

__device__ __forceinline__ u16 f2h_bits(float v) {
    union { _Float16 h; u16 u; } c;
    c.h = (_Float16)v;
    return c.u;
}

// ---------------------------------------------------------------------------
// Swizzled "fragment-major" fp16 storage for a [R x K] matrix:
//   chunk (rt, kt) with rt=r>>5, kt=k>>4; nKT = K>>4; chunk = 512 halfs (1KB)
//   element (r,k) at: ((size_t)rt*nKT + kt)*512 + ((r&31) + 32*((k&15)>>3))*8 + (k&7)
// A wave reading `chunkbase + lane*8` gets exactly the 32x32x16 MFMA A/B
// fragment (layout correctness-verified in r2-r5 as the LDS chunk layout;
// here it lives in global memory so the K-loop needs NO LDS and NO barriers).
// ---------------------------------------------------------------------------

// fp32 [R x CK] row-major -> swizzled fp16. Tile 32 rows x 128 cols per block.
__global__ __launch_bounds__(256) void cast_swizzle(const float* __restrict__ in,
                                                    u16* __restrict__ out, int CK) {
    __shared__ u16 t[32 * 132];                  // rows padded to 132 halfs
    const int tid = threadIdx.x;
    const int r0 = blockIdx.x * 32, c0 = blockIdx.y * 128;
#pragma unroll
    for (int p = 0; p < 4; ++p) {
        int lin = (p * 256 + tid) * 4;
        int r = lin >> 7, c = lin & 127;
        float4 v = *(const float4*)&in[(size_t)(r0 + r) * CK + c0 + c];
        half4v o = { (_Float16)v.x, (_Float16)v.y, (_Float16)v.z, (_Float16)v.w };
        *(half4v*)&t[r * 132 + c] = o;
    }
    __syncthreads();
    const int nKT = CK >> 4;
#pragma unroll
    for (int q = 0; q < 2; ++q) {
        int s = q * 256 + tid;
        int ch = s >> 6, L = s & 63;
        int rw = L & 31, hh = L >> 5;
        half4v v0 = *(const half4v*)&t[rw * 132 + ch * 16 + hh * 8];
        half4v v1 = *(const half4v*)&t[rw * 132 + ch * 16 + hh * 8 + 4];
        size_t base = ((size_t)(r0 >> 5) * nKT + (c0 >> 4) + ch) * 512 + (size_t)L * 8;
        *(half4v*)&out[base]     = v0;
        *(half4v*)&out[base + 4] = v1;
    }
}

// W [K,D] fp32 -> Wt swizzled fp16 ([D rows, K cols] fragment-major).
__global__ __launch_bounds__(256) void transpose_cast(const float* __restrict__ in,
                                                      u16* __restrict__ out,
                                                      int K, int D) {
    __shared__ float tile[32][33];
    int tx = threadIdx.x & 31;
    int ty = threadIdx.x >> 5;                  // 0..7
    int d0 = blockIdx.x * 32, k0 = blockIdx.y * 32;
#pragma unroll
    for (int i = 0; i < 32; i += 8)
        tile[ty + i][tx] = in[(size_t)(k0 + ty + i) * D + d0 + tx];
    __syncthreads();
    const int nKT = K >> 4;
#pragma unroll
    for (int i = 0; i < 32; i += 8) {
        int d = ty + i;                          // row within 32-tile
        size_t ch = (size_t)(d0 >> 5) * nKT + (k0 >> 4) + (tx >> 4);
        int slot = d + 32 * ((tx >> 3) & 1);
        out[ch * 512 + slot * 8 + (tx & 7)] = f2h_bits(tile[tx][d]);
    }
}

// ---------------------------------------------------------------------------
// Flat (LDS-free, barrier-free) 128x128-tile GEMM. 256 threads = 4 waves 2x2,
// each wave computes 64x64 via 2x2 of 32x32x16 f16 MFMA. A [M,K] and B [N,K]
// both swizzled fragment-major; fragments loaded straight to VGPRs with
// coalesced global_load_dwordx4 (chunkbase + lane*16B). 4-stage register
// pipeline; compiler inserts fine-grained vmcnt (no barrier forces vmcnt(0)).
// XCD-banded 1D grid retained (r3/r4: FETCH at compulsory minimum).
//
// MODE 0: C[M,N] = A@B + bias   (fp16 out, SWIZZLED fragment-major)
// MODE 1: Lacc[row] += sum_col (A@B + bias - Xref)^2   (Xref swizzled fp16)
template <int MODE>
__global__ __launch_bounds__(256, 2) void gemm_flat(
    const u16* __restrict__ A, const u16* __restrict__ B,
    const float* __restrict__ bias,
    u16* __restrict__ C, const u16* __restrict__ Xref,
    float* __restrict__ Lacc,
    int M, int N, int K, int NT, int P) {
    const int tid  = threadIdx.x;
    const int lane = tid & 63;
    const int w    = tid >> 6;
    const int wr   = w >> 1, wc = w & 1;
    const int l31 = lane & 31, h = lane >> 5;

    // ---- XCD-banded tile decode ----
    const int b    = blockIdx.x;
    const int xcd  = b & 7;
    const int slot = b >> 3;
    const int perPanel = NT * P;
    const int p    = slot / perPanel;
    const int rem  = slot - p * perPanel;
    const int n_t  = rem / P;
    const int mi   = rem - n_t * P;
    const int mPerX = (M >> 7) >> 3;               // (M/128)/8
    const int m0 = (xcd * mPerX + p * P + mi) * 128;
    const int n0 = n_t * 128;

    const int nKT = K >> 4;                        // k-chunks (64 or 128)
    const u16* a0 = A + ((size_t)((m0 >> 5) + wr * 2 + 0) * nKT) * 512 + (size_t)lane * 8;
    const u16* a1 = A + ((size_t)((m0 >> 5) + wr * 2 + 1) * nKT) * 512 + (size_t)lane * 8;
    const u16* b0 = B + ((size_t)((n0 >> 5) + wc * 2 + 0) * nKT) * 512 + (size_t)lane * 8;
    const u16* b1 = B + ((size_t)((n0 >> 5) + wc * 2 + 1) * nKT) * 512 + (size_t)lane * 8;

    f32x16 acc[2][2] = {};
    half8 Aq[4][2], Bq[4][2];
#pragma unroll
    for (int s = 0; s < 4; ++s) {
        Aq[s][0] = *(const half8*)(a0 + s * 512);
        Aq[s][1] = *(const half8*)(a1 + s * 512);
        Bq[s][0] = *(const half8*)(b0 + s * 512);
        Bq[s][1] = *(const half8*)(b1 + s * 512);
    }

    for (int kc = 0; kc < nKT; kc += 4) {          // nKT % 4 == 0
        const bool more = (kc + 4 < nKT);
#pragma unroll
        for (int s = 0; s < 4; ++s) {
            acc[0][0] = __builtin_amdgcn_mfma_f32_32x32x16_f16(Aq[s][0], Bq[s][0], acc[0][0], 0, 0, 0);
            acc[0][1] = __builtin_amdgcn_mfma_f32_32x32x16_f16(Aq[s][0], Bq[s][1], acc[0][1], 0, 0, 0);
            acc[1][0] = __builtin_amdgcn_mfma_f32_32x32x16_f16(Aq[s][1], Bq[s][0], acc[1][0], 0, 0, 0);
            acc[1][1] = __builtin_amdgcn_mfma_f32_32x32x16_f16(Aq[s][1], Bq[s][1], acc[1][1], 0, 0, 0);
            if (more) {
                int kn = kc + 4 + s;
                Aq[s][0] = *(const half8*)(a0 + kn * 512);
                Aq[s][1] = *(const half8*)(a1 + kn * 512);
                Bq[s][0] = *(const half8*)(b0 + kn * 512);
                Bq[s][1] = *(const half8*)(b1 + kn * 512);
            }
        }
    }

    // ---- epilogue ----
    // C/D layout (verified r2-r5): col = n0+wc*64+j*32+l31,
    // row = m0+wr*64+i*32 + 4*h + (r&3) + 8*(r>>2).
    // Swizzled address pieces for output-shaped matrices ([M x N], nNT=N>>4):
    const int nNT = N >> 4;
    const int cb  = n0 + wc * 64 + l31;
    float bj0 = bias[cb], bj1 = bias[cb + 32];
    const int inslot = ((l31 >> 3) & 1) * 256 + (l31 & 7);   // halfs within chunk
    const int ct0 = (n0 >> 4) + wc * 4 + (l31 >> 4);         // col chunk, j=0

    if (MODE == 0) {
#pragma unroll
        for (int i = 0; i < 2; ++i) {
            size_t rowChunk = (size_t)((m0 >> 5) + wr * 2 + i) * nNT;
            size_t base0 = (rowChunk + ct0) * 512 + inslot;
            size_t base1 = base0 + 2 * 512;                  // j=1: col+32 -> chunk+2
#pragma unroll
            for (int r = 0; r < 16; ++r) {
                int rb = 4 * h + (r & 3) + 8 * (r >> 2);     // row & 31
                C[base0 + rb * 8] = f2h_bits(acc[i][0][r] + bj0);
                C[base1 + rb * 8] = f2h_bits(acc[i][1][r] + bj1);
            }
        }
    } else {
#pragma unroll
        for (int i = 0; i < 2; ++i) {
            size_t rowChunk = (size_t)((m0 >> 5) + wr * 2 + i) * nNT;
            size_t base0 = (rowChunk + ct0) * 512 + inslot;
            size_t base1 = base0 + 2 * 512;
            int rowb = m0 + wr * 64 + i * 32 + 4 * h;
#pragma unroll
            for (int r = 0; r < 16; ++r) {
                int rb = 4 * h + (r & 3) + 8 * (r >> 2);
                float x0 = (float)(*(const _Float16*)&Xref[base0 + rb * 8]);
                float x1 = (float)(*(const _Float16*)&Xref[base1 + rb * 8]);
                float d0 = acc[i][0][r] + bj0 - x0;
                float d1 = acc[i][1][r] + bj1 - x1;
                float s = d0 * d0 + d1 * d1;
                // reduce over the 32 lanes (cols) sharing this row
                s += __shfl_xor(s, 1, 64);
                s += __shfl_xor(s, 2, 64);
                s += __shfl_xor(s, 4, 64);
                s += __shfl_xor(s, 8, 64);
                s += __shfl_xor(s, 16, 64);
                if (l31 == 0)
                    atomicAdd(&Lacc[rowb + (r & 3) + 8 * (r >> 2)], s);
            }
        }
    }
}

// ---------------------------------------------------------------------------
// Per-row L3 = sum (h1-h2)^2 and L4row = sum (h1+h2)*whoW. One block per row.
// H1/H2 are SWIZZLED [NR x DH]: thread tid covers k = tid*8..+8:
// kt = tid>>1, hbit = tid&1.
__global__ __launch_bounds__(256) void l34_kernel(
    const u16* __restrict__ H1, const u16* __restrict__ H2,
    const float* __restrict__ whoW,
    float* __restrict__ L3, float* __restrict__ L4) {
    int row = blockIdx.x;
    int tid = threadIdx.x;
    size_t base = ((size_t)(row >> 5) * (DH >> 4) + (tid >> 1)) * 512
                + (size_t)((row & 31) + 32 * (tid & 1)) * 8;
    const half8 h1 = *(const half8*)&H1[base];
    const half8 h2 = *(const half8*)&H2[base];
    float4 w0 = *(const float4*)&whoW[tid * 8];
    float4 w1 = *(const float4*)&whoW[tid * 8 + 4];
    float wv[8] = { w0.x, w0.y, w0.z, w0.w, w1.x, w1.y, w1.z, w1.w };
    float s3 = 0.f, s4 = 0.f;
#pragma unroll
    for (int u = 0; u < 8; ++u) {
        float a = (float)h1[u], b = (float)h2[u];
        float d = a - b;
        s3 += d * d;
        s4 += (a + b) * wv[u];
    }
#pragma unroll
    for (int off = 1; off < 64; off <<= 1) {
        s3 += __shfl_xor(s3, off, 64);
        s4 += __shfl_xor(s4, off, 64);
    }
    __shared__ float sm[8];
    int wvi = tid >> 6, ln = tid & 63;
    if (ln == 0) { sm[wvi] = s3; sm[4 + wvi] = s4; }
    __syncthreads();
    if (tid == 0) {
        L3[row] = sm[0] + sm[1] + sm[2] + sm[3];
        L4[row] = sm[4] + sm[5] + sm[6] + sm[7];
    }
}

// ---------------------------------------------------------------------------
// loss = sum_r L1^2 + L2^2 + L3^2 + (0.5*(L4row + who_b) - Y)^2
__global__ __launch_bounds__(1024) void final_reduce(
    const float* __restrict__ L1, const float* __restrict__ L2,
    const float* __restrict__ L3, const float* __restrict__ L4,
    const float* __restrict__ Y, const float* __restrict__ whob,
    float* __restrict__ out) {
    float s = 0.f;
    float wb = whob[0];
    for (int r = threadIdx.x; r < NR; r += 1024) {
        float l4 = 0.5f * (L4[r] + wb) - Y[r];
        s += L1[r] * L1[r] + L2[r] * L2[r] + L3[r] * L3[r] + l4 * l4;
    }
#pragma unroll
    for (int off = 1; off < 64; off <<= 1) s += __shfl_xor(s, off, 64);
    __shared__ float sm[16];
    int w = threadIdx.x >> 6, ln = threadIdx.x & 63;
    if (ln == 0) sm[w] = s;
    __syncthreads();
    if (threadIdx.x == 0) {
        float t = 0.f;
#pragma unroll
        for (int i = 0; i < 16; ++i) t += sm[i];
        out[0] = t;
    }
}

// ---------------------------------------------------------------------------
extern "C" void kernel_launch(void* const* d_in, const int* in_sizes, int n_in,
                              void* d_out, int out_size, void* d_ws, size_t ws_size,
                              hipStream_t stream) {
    const float* X1   = (const float*)d_in[0];
    const float* X2   = (const float*)d_in[1];
    const float* Y    = (const float*)d_in[2];
    const float* w1hW = (const float*)d_in[3];
    const float* w1hb = (const float*)d_in[4];
    const float* w2hW = (const float*)d_in[5];
    const float* w2hb = (const float*)d_in[6];
    const float* wh1W = (const float*)d_in[7];
    const float* wh1b = (const float*)d_in[8];
    const float* wh2W = (const float*)d_in[9];
    const float* wh2b = (const float*)d_in[10];
    const float* whoW = (const float*)d_in[11];
    const float* whob = (const float*)d_in[12];

    // workspace layout (~208.3 MB total, all fp16 matrices SWIZZLED)
    char* ws = (char*)d_ws;
    u16* X1h  = (u16*)(ws);                               // 16384x1024
    u16* X2h  = X1h + (size_t)NR * DX;
    u16* H1h  = X2h + (size_t)NR * DX;                    // 16384x2048
    u16* H2h  = H1h + (size_t)NR * DH;
    u16* w1hT = H2h + (size_t)NR * DH;                    // [DH x DX]
    u16* w2hT = w1hT + (size_t)DH * DX;
    u16* wh1T = w2hT + (size_t)DH * DX;                   // [DX x DH]
    u16* wh2T = wh1T + (size_t)DX * DH;
    float* L1a = (float*)(wh2T + (size_t)DX * DH);        // 4 x 16384 f32
    float* L2a = L1a + NR;
    float* L3a = L2a + NR;
    float* L4a = L3a + NR;

    // zero the atomically-accumulated arrays (ws is poisoned 0xAA each call)
    hipMemsetAsync(L1a, 0, 2 * (size_t)NR * sizeof(float), stream);

    // casts (fp32 -> swizzled fp16)
    cast_swizzle<<<dim3(NR / 32, DX / 128), 256, 0, stream>>>(X1, X1h, DX);
    cast_swizzle<<<dim3(NR / 32, DX / 128), 256, 0, stream>>>(X2, X2h, DX);
    transpose_cast<<<dim3(DH / 32, DX / 32), 256, 0, stream>>>(w1hW, w1hT, DX, DH);
    transpose_cast<<<dim3(DH / 32, DX / 32), 256, 0, stream>>>(w2hW, w2hT, DX, DH);
    transpose_cast<<<dim3(DX / 32, DH / 32), 256, 0, stream>>>(wh1W, wh1T, DH, DX);
    transpose_cast<<<dim3(DX / 32, DH / 32), 256, 0, stream>>>(wh2W, wh2T, DH, DX);

    // H1 = X1@w1h + b, H2 = X2@w2h + b  (swizzled fp16 out). N=DH: NT=16, P=8.
    gemm_flat<0><<<(NR / 128) * (DH / 128), 256, 0, stream>>>(
        X1h, w1hT, w1hb, H1h, nullptr, nullptr, NR, DH, DX, DH / 128, 8);
    gemm_flat<0><<<(NR / 128) * (DH / 128), 256, 0, stream>>>(
        X2h, w2hT, w2hb, H2h, nullptr, nullptr, NR, DH, DX, DH / 128, 8);

    // L3, L4row from H1, H2
    l34_kernel<<<NR, 256, 0, stream>>>(H1h, H2h, whoW, L3a, L4a);

    // L1 = rowsq(H1@wh2 + b - X2), L2 = rowsq(H2@wh1 + b - X1). N=DX: NT=8, P=4.
    gemm_flat<1><<<(NR / 128) * (DX / 128), 256, 0, stream>>>(
        H1h, wh2T, wh2b, nullptr, X2h, L1a, NR, DX, DH, DX / 128, 4);
    gemm_flat<1><<<(NR / 128) * (DX / 128), 256, 0, stream>>>(
        H2h, wh1T, wh1b, nullptr, X1h, L2a, NR, DX, DH, DX / 128, 4);

    final_reduce<<<1, 1024, 0, stream>>>(L1a, L2a, L3a, L4a, Y, whob, (float*)d_out);
}